// Round 13
// baseline (192.446 us; speedup 1.0000x reference)
//
#include <hip/hip_runtime.h>
#include <hip/hip_fp16.h>
#include <math.h>

#define KGRID 1024
#define NIMG  512
#define JW    6
#define BETAF 14.04f   // 2.34 * J
#define NB    8        // batch count (fixed by problem)
#define NBIN  16384    // 128 x 128 tiles (8x8 cells, lane=cell)
#define CAP   96       // max entries per bin (mean ~33, uniform uv)

// ---------- Kaiser-Bessel I0 (Abramowitz & Stegun 9.8.1 / 9.8.2, ~2e-7 rel) ----------
__device__ __forceinline__ float i0f_dev(float x) {
    float ax = fabsf(x);
    if (ax < 3.75f) {
        float z = ax * (1.0f / 3.75f);
        z = z * z;
        return 1.0f + z * (3.5156229f + z * (3.0899424f + z * (1.2067492f +
               z * (0.2659732f + z * (0.0360768f + z * 0.0045813f)))));
    } else {
        float z = 3.75f / ax;
        float p = 0.39894228f + z * (0.01328592f + z * (0.00225319f + z * (-0.00157565f +
                  z * (0.00916281f + z * (-0.02057706f + z * (0.02635537f +
                  z * (-0.01647633f + z * 0.00392377f)))))));
        return expf(ax) * rsqrtf(ax) * p;
    }
}

// ---------- Phase 0: precompute weights/meta + y lines + gather-bin (8x8 tiles) ----------
// pnt line slots: [0..5]=wx*sc, [6]=x0 bits, [7]=y0 bits, [8..13]=wy, [14]=[15]=0.
// Entry m=M is an all-zero dummy line (pipeline padding).
__global__ __launch_bounds__(256) void prep_kernel(
    const float* __restrict__ yr, const float* __restrict__ yi,
    const float* __restrict__ uv, const float* __restrict__ wts,
    float4* __restrict__ yF4, float4* __restrict__ pnt,
    int* __restrict__ cnt, int* __restrict__ list, int M)
{
    int m = blockIdx.x * 256 + threadIdx.x;
    if (m >= M) return;

    if (m == 0) {   // dummy point at index M: zero weights, zero y
        float4 z = make_float4(0.f, 0.f, 0.f, 0.f);
        #pragma unroll
        for (int q = 0; q < 4; q++) { pnt[(size_t)M * 4 + q] = z; yF4[(size_t)M * 4 + q] = z; }
    }

    float inv = 1.0f / i0f_dev(BETAF);
    float s2 = inv * inv;

    #pragma unroll
    for (int bp = 0; bp < 4; bp++) {
        int b0 = 2 * bp;
        yF4[(size_t)m * 4 + bp] = make_float4(
            yr[(size_t)b0 * M + m],       yi[(size_t)b0 * M + m],
            yr[(size_t)(b0 + 1) * M + m], yi[(size_t)(b0 + 1) * M + m]);
    }

    float u = uv[2 * m], v = uv[2 * m + 1];
    float sc = wts[m] * s2;
    const float c2g = (float)KGRID / 6.283185307179586f;
    float kx = u * c2g, ky = v * c2g;
    float kmx = floorf(kx - 3.0f), kmy = floorf(ky - 3.0f);
    int x0m = (((int)kmx + 1) + 1024) & 1023;
    int y0m = (((int)kmy + 1) + 1024) & 1023;

    float wx[JW], wy[JW];
    #pragma unroll
    for (int j = 0; j < JW; j++) {
        float dx = kx - kmx - 1.0f - (float)j;
        float rx = dx * (1.0f / 3.0f);
        float ax = fmaxf(1.0f - rx * rx, 0.0f);
        wx[j] = i0f_dev(BETAF * sqrtf(ax)) * sc;
        float dy = ky - kmy - 1.0f - (float)j;
        float ry = dy * (1.0f / 3.0f);
        float ay = fmaxf(1.0f - ry * ry, 0.0f);
        wy[j] = i0f_dev(BETAF * sqrtf(ay));
    }

    float4* p = pnt + (size_t)m * 4;
    p[0] = make_float4(wx[0], wx[1], wx[2], wx[3]);
    p[1] = make_float4(wx[4], wx[5], __int_as_float(x0m), __int_as_float(y0m));
    p[2] = make_float4(wy[0], wy[1], wy[2], wy[3]);
    p[3] = make_float4(wy[4], wy[5], 0.0f, 0.0f);

    // gather-bin (8x8): footprint 6 wide crosses next tile iff in-tile offset >= 3
    int txA = x0m >> 3, txB = (txA + 1) & 127;
    int tyA = y0m >> 3, tyB = (tyA + 1) & 127;
    bool bx = (x0m & 7) >= 3;
    bool by = (y0m & 7) >= 3;

    #define PUSH(tx, ty) { int bin = ((tx) << 7) | (ty);                 \
                           int slot = atomicAdd(&cnt[bin], 1);           \
                           if (slot < CAP) list[bin * CAP + slot] = m; }
    PUSH(txA, tyA);
    if (by)  PUSH(txA, tyB);
    if (bx) { PUSH(txB, tyA); if (by) PUSH(txB, tyB); }
    #undef PUSH
}

// ---------- Phase B: gather-gridding, lane=cell, register accumulation ----------
// One wave per 8x8 tile; acc fp32, flush fp16 planes. Depth-3 prefetch (y loads
// are wave-uniform -> s_load; 3 stages cover ~200cyc L2 latency).
__global__ __launch_bounds__(256) void grid_tile(
    const float* __restrict__ pnt1, const float4* __restrict__ yF4,
    const int* __restrict__ cnt, const int* __restrict__ list,
    __half2* __restrict__ gH, int M)
{
    int lane = threadIdx.x & 63;
    int wid  = threadIdx.x >> 6;
    int tile = blockIdx.x * 4 + wid;
    int tx0 = (tile >> 7) << 3;
    int ty0 = (tile & 127) << 3;
    int lx = lane >> 3, ly = lane & 7;
    int slot = lane & 15;

    float2 acc[NB];
    #pragma unroll
    for (int b = 0; b < NB; b++) acc[b] = make_float2(0.f, 0.f);

    int n = cnt[tile]; if (n > CAP) n = CAP;
    const int* lst = list + tile * CAP;

    // preload index list into 2 VGPRs (slots beyond n -> dummy M)
    int lv0 = (lane < n) ? lst[lane] : M;
    int lv1 = (64 + lane < n && 64 + lane < CAP) ? lst[64 + lane] : M;

    #define FETCH_M(i) __builtin_amdgcn_readlane(((i) < 64) ? lv0 : lv1, (i) & 63)

    int   mA = FETCH_M(0), mB = FETCH_M(1), mC = FETCH_M(2);
    float pwA = pnt1[(size_t)mA * 16 + slot];
    float pwB = pnt1[(size_t)mB * 16 + slot];
    float pwC = pnt1[(size_t)mC * 16 + slot];
    float4 yA0 = yF4[(size_t)mA * 4 + 0], yA1 = yF4[(size_t)mA * 4 + 1],
           yA2 = yF4[(size_t)mA * 4 + 2], yA3 = yF4[(size_t)mA * 4 + 3];
    float4 yB0 = yF4[(size_t)mB * 4 + 0], yB1 = yF4[(size_t)mB * 4 + 1],
           yB2 = yF4[(size_t)mB * 4 + 2], yB3 = yF4[(size_t)mB * 4 + 3];
    float4 yC0 = yF4[(size_t)mC * 4 + 0], yC1 = yF4[(size_t)mC * 4 + 1],
           yC2 = yF4[(size_t)mC * 4 + 2], yC3 = yF4[(size_t)mC * 4 + 3];

    for (int i = 0; i < n; i++) {
        int mD = FETCH_M(i + 3);
        float pwD = pnt1[(size_t)mD * 16 + slot];
        float4 yD0 = yF4[(size_t)mD * 4 + 0], yD1 = yF4[(size_t)mD * 4 + 1],
               yD2 = yF4[(size_t)mD * 4 + 2], yD3 = yF4[(size_t)mD * 4 + 3];

        int pwb = __float_as_int(pwA);
        int x0 = __builtin_amdgcn_readlane(pwb, 6);
        int y0 = __builtin_amdgcn_readlane(pwb, 7);
        int j1 = (tx0 + lx - x0) & 1023;
        int j2 = (ty0 + ly - y0) & 1023;
        int i1 = (j1 < 6) ? j1 : 15;            // slot 15 = 0
        int i2 = (j2 < 6) ? (j2 + 8) : 14;      // slot 14 = 0
        float wx = __int_as_float(__builtin_amdgcn_ds_bpermute(i1 << 2, pwb));
        float wy = __int_as_float(__builtin_amdgcn_ds_bpermute(i2 << 2, pwb));
        float w = wx * wy;

        acc[0].x = fmaf(w, yA0.x, acc[0].x); acc[0].y = fmaf(w, yA0.y, acc[0].y);
        acc[1].x = fmaf(w, yA0.z, acc[1].x); acc[1].y = fmaf(w, yA0.w, acc[1].y);
        acc[2].x = fmaf(w, yA1.x, acc[2].x); acc[2].y = fmaf(w, yA1.y, acc[2].y);
        acc[3].x = fmaf(w, yA1.z, acc[3].x); acc[3].y = fmaf(w, yA1.w, acc[3].y);
        acc[4].x = fmaf(w, yA2.x, acc[4].x); acc[4].y = fmaf(w, yA2.y, acc[4].y);
        acc[5].x = fmaf(w, yA2.z, acc[5].x); acc[5].y = fmaf(w, yA2.w, acc[5].y);
        acc[6].x = fmaf(w, yA3.x, acc[6].x); acc[6].y = fmaf(w, yA3.y, acc[6].y);
        acc[7].x = fmaf(w, yA3.z, acc[7].x); acc[7].y = fmaf(w, yA3.w, acc[7].y);

        pwA = pwB; yA0 = yB0; yA1 = yB1; yA2 = yB2; yA3 = yB3;
        pwB = pwC; yB0 = yC0; yB1 = yC1; yB2 = yC2; yB3 = yC3;
        pwC = pwD; yC0 = yD0; yC1 = yD1; yC2 = yD2; yC3 = yD3;
    }
    #undef FETCH_M

    // flush fp16: tiles partition the grid -> every cell written exactly once
    size_t cell = ((size_t)(tx0 + lx) << 10) + (size_t)(ty0 + ly);
    #pragma unroll
    for (int b = 0; b < NB; b++)
        gH[((size_t)b << 20) + cell] = __float22half2_rn(acc[b]);
}

// ---------- Stockham radix-2 1024-pt inverse (e^{+i}) FFT in LDS ----------
__device__ __forceinline__ void fft1024_inv(float2* X, float2* Y, const float2* W, int tid)
{
    float2* src = X;
    float2* dst = Y;
    #pragma unroll
    for (int stage = 0; stage < 10; stage++) {
        const int s = 1 << stage;
        __syncthreads();
        #pragma unroll
        for (int h = 0; h < 2; h++) {
            int t  = tid + (h << 8);
            int sp = t & ~(s - 1);
            float2 c0 = src[t];
            float2 c1 = src[t + 512];
            float2 sum = make_float2(c0.x + c1.x, c0.y + c1.y);
            float2 dif = make_float2(c0.x - c1.x, c0.y - c1.y);
            float2 w = W[sp];
            dst[t + sp]     = sum;
            dst[t + sp + s] = make_float2(w.x * dif.x - w.y * dif.y,
                                          w.x * dif.y + w.y * dif.x);
        }
        float2* tmp = src; src = dst; dst = tmp;
    }
    __syncthreads();
}

// ---------- Pass 1 (fused Hermitian pack, mirror-paired): rows k2 -> x2 ----------
// Block g handles 8 output rows: {4g..4g+3} and {1020-4g..1023-4g}; mirror rows
// reuse the base rows' sources (L2 hits) -> ~10 unique row reads per plane.
__global__ __launch_bounds__(256) void fft_pass1(const __half2* __restrict__ gH,
                                                 __half2* __restrict__ T)
{
    __shared__ float2 A[1024];
    __shared__ float2 Bb[1024];
    __shared__ float2 W[512];
    __shared__ __half2 R[8][512];

    int blk = blockIdx.x;
    int p   = blk >> 7;          // 4 packed plane-pairs
    int g   = blk & 127;
    int tid = threadIdx.x;

    #pragma unroll
    for (int h = 0; h < 2; h++) {
        int j = tid + (h << 8);
        float sn, cn;
        __sincosf(6.283185307179586f * (float)j * (1.0f / 1024.0f), &sn, &cn);
        W[j] = make_float2(cn, sn);
    }

    const __half2* gA = gH + ((size_t)(2 * p)     << 20);
    const __half2* gB = gH + ((size_t)(2 * p + 1) << 20);

    for (int f = 0; f < 8; f++) {
        int k1  = (f < 4) ? (4 * g + f) : (1020 - 4 * g + (f - 4));
        int nk1 = (1024 - k1) & 1023;
        const __half2* rA  = gA + ((size_t)k1  << 10);
        const __half2* rAn = gA + ((size_t)nk1 << 10);
        const __half2* rB  = gB + ((size_t)k1  << 10);
        const __half2* rBn = gB + ((size_t)nk1 << 10);
        __syncthreads();
        #pragma unroll
        for (int h = 0; h < 4; h++) {
            int k2  = tid + (h << 8);
            int nk2 = (1024 - k2) & 1023;
            float2 va  = __half22float2(rA[k2]);
            float2 van = __half22float2(rAn[nk2]);
            float2 vb  = __half22float2(rB[k2]);
            float2 vbn = __half22float2(rBn[nk2]);
            A[k2] = make_float2(0.5f * (va.x + van.x) - 0.5f * (vb.y - vbn.y),
                                0.5f * (va.y - van.y) + 0.5f * (vb.x + vbn.x));
        }
        fft1024_inv(A, Bb, W, tid);
        #pragma unroll
        for (int h = 0; h < 2; h++) {
            int xo2 = tid + (h << 8);
            R[f][xo2] = __float22half2_rn(A[(xo2 + 768) & 1023]);
        }
    }
    __syncthreads();

    // T layout: half2 T[p][xo2][k1]; both quads contiguous -> 16B stores
    #pragma unroll
    for (int h = 0; h < 2; h++) {
        int xo2 = tid + (h << 8);
        __half2* Trow = T + (((size_t)p * 512 + xo2) << 10);
        int4 q0, q1;
        q0.x = *(const int*)&R[0][xo2]; q0.y = *(const int*)&R[1][xo2];
        q0.z = *(const int*)&R[2][xo2]; q0.w = *(const int*)&R[3][xo2];
        q1.x = *(const int*)&R[4][xo2]; q1.y = *(const int*)&R[5][xo2];
        q1.z = *(const int*)&R[6][xo2]; q1.w = *(const int*)&R[7][xo2];
        *(int4*)(Trow + 4 * g)          = q0;
        *(int4*)(Trow + (1020 - 4 * g)) = q1;
    }
}

// ---------- de-apodization (matches _deapod) ----------
__device__ __forceinline__ float apodf(int n) {
    float x  = ((float)n - 256.0f) * (1.0f / 1024.0f);
    float px = 3.14159265358979f * 6.0f * x;
    float t  = BETAF * BETAF - px * px;
    float st = sqrtf(fabsf(t));
    float num = (t > 0.0f) ? sinhf(st) : __sinf(st);
    return num / fmaxf(st, 1e-6f);
}

// ---------- Pass 2: columns (k1 -> x1) of packed planes, 4 cols/block;
// real -> batch 2p, imag -> batch 2p+1; coalesced float4 stores ----------
__global__ __launch_bounds__(256) void fft_pass2(const __half2* __restrict__ T,
                                                 float* __restrict__ out)
{
    __shared__ float2 A[1024];
    __shared__ float2 Bb[1024];
    __shared__ float2 W[512];
    __shared__ float2 R[4][512];

    int blk = blockIdx.x;
    int p   = blk >> 7;
    int xg  = blk & 127;
    int tid = threadIdx.x;

    #pragma unroll
    for (int h = 0; h < 2; h++) {
        int j = tid + (h << 8);
        float sn, cn;
        __sincosf(6.283185307179586f * (float)j * (1.0f / 1024.0f), &sn, &cn);
        W[j] = make_float2(cn, sn);
    }

    float a2[4];
    #pragma unroll
    for (int r = 0; r < 4; r++) a2[r] = apodf((xg << 2) + r);

    for (int r = 0; r < 4; r++) {
        int xo2 = (xg << 2) + r;
        const __half2* row = T + (((size_t)p * 512 + xo2) << 10);
        __syncthreads();
        #pragma unroll
        for (int h = 0; h < 4; h++) {
            int i = tid + (h << 8);
            A[i] = __half22float2(row[i]);
        }
        fft1024_inv(A, Bb, W, tid);
        #pragma unroll
        for (int h = 0; h < 2; h++) {
            int xo1 = tid + (h << 8);
            float2 v = A[(xo1 + 768) & 1023];
            R[r][xo1] = make_float2(v.x / a2[r], v.y / a2[r]);
        }
    }
    __syncthreads();

    int b0 = 2 * p;
    #pragma unroll
    for (int h = 0; h < 2; h++) {
        int xo1 = tid + (h << 8);
        float inva1 = 1.0f / apodf(xo1);
        float2 f0 = R[0][xo1], f1 = R[1][xo1], f2 = R[2][xo1], f3 = R[3][xo1];
        float4* o0 = (float4*)(out + (((size_t)b0 * 512 + xo1) << 9) + (xg << 2));
        float4* o1 = (float4*)(out + (((size_t)(b0 + 1) * 512 + xo1) << 9) + (xg << 2));
        *o0 = make_float4(f0.x * inva1, f1.x * inva1, f2.x * inva1, f3.x * inva1);
        *o1 = make_float4(f0.y * inva1, f1.y * inva1, f2.y * inva1, f3.y * inva1);
    }
}

// ---------- host launch ----------
extern "C" void kernel_launch(void* const* d_in, const int* in_sizes, int n_in,
                              void* d_out, int out_size, void* d_ws, size_t ws_size,
                              hipStream_t stream)
{
    const float* yr  = (const float*)d_in[0];
    const float* yi  = (const float*)d_in[1];
    const float* uv  = (const float*)d_in[2];
    const float* wts = (const float*)d_in[3];

    int M = in_sizes[3];

    // ws layout (non-overlapping):
    //  [0,32)MB : gH (8 fp16 planar grids, 4 MB each)
    //  [32,40)MB: T (fp16, 8 MB)
    //  [64,96)MB: prep/grid scratch (cnt/list/yF4/pnt)
    __half2* gH = (__half2*)d_ws;
    __half2* T  = (__half2*)((char*)d_ws + ((size_t)32 << 20));
    char*    p2 = (char*)d_ws + ((size_t)64 << 20);
    int*    cnt  = (int*)p2;                                     // 64 KB
    int*    list = (int*)(p2 + 65536);                           // 6.29 MB
    float4* yF4  = (float4*)(p2 + 6553600);                      // 12.8 MB (M+1 pts)
    float4* pnt  = (float4*)(p2 + 19500032);                     // 12.8 MB (M+1 pts)

    hipMemsetAsync(cnt, 0, NBIN * sizeof(int), stream);
    prep_kernel<<<dim3((M + 255) / 256), dim3(256), 0, stream>>>(
        yr, yi, uv, wts, yF4, pnt, cnt, list, M);
    grid_tile<<<dim3(NBIN / 4), dim3(256), 0, stream>>>(
        (const float*)pnt, (const float4*)yF4, cnt, list, gH, M);
    fft_pass1<<<dim3(4 * 128), dim3(256), 0, stream>>>(gH, T);
    fft_pass2<<<dim3(4 * 128), dim3(256), 0, stream>>>(T, (float*)d_out);
}

// Round 14
// 188.886 us; speedup vs baseline: 1.0188x; 1.0188x over previous
//
#include <hip/hip_runtime.h>
#include <hip/hip_fp16.h>
#include <math.h>

#define KGRID 1024
#define NIMG  512
#define JW    6
#define BETAF 14.04f   // 2.34 * J
#define NB    8        // batch count (fixed by problem)
#define NBIN  16384    // 128 x 128 tiles (8x8 cells, lane=cell)
#define CAP   96       // max entries per bin (mean ~33, uniform uv)

// ---------- Kaiser-Bessel I0 (Abramowitz & Stegun 9.8.1 / 9.8.2, ~2e-7 rel) ----------
__device__ __forceinline__ float i0f_dev(float x) {
    float ax = fabsf(x);
    if (ax < 3.75f) {
        float z = ax * (1.0f / 3.75f);
        z = z * z;
        return 1.0f + z * (3.5156229f + z * (3.0899424f + z * (1.2067492f +
               z * (0.2659732f + z * (0.0360768f + z * 0.0045813f)))));
    } else {
        float z = 3.75f / ax;
        float p = 0.39894228f + z * (0.01328592f + z * (0.00225319f + z * (-0.00157565f +
                  z * (0.00916281f + z * (-0.02057706f + z * (0.02635537f +
                  z * (-0.01647633f + z * 0.00392377f)))))));
        return expf(ax) * rsqrtf(ax) * p;
    }
}

// ---------- Phase 0: precompute weights/meta + y lines + gather-bin (8x8 tiles) ----------
// pnt line slots: [0..5]=wx*sc, [6]=x0 bits, [7]=y0 bits, [8..13]=wy, [14]=[15]=0.
// Entry m=M is an all-zero dummy line (pipeline padding).
// Binning: all four atomicAdds are hoisted above the list stores so their L2
// round-trips overlap (was: 4 serialized atomic->store chains -> latency-bound).
__global__ __launch_bounds__(256) void prep_kernel(
    const float* __restrict__ yr, const float* __restrict__ yi,
    const float* __restrict__ uv, const float* __restrict__ wts,
    float4* __restrict__ yF4, float4* __restrict__ pnt,
    int* __restrict__ cnt, int* __restrict__ list, int M)
{
    int m = blockIdx.x * 256 + threadIdx.x;
    if (m >= M) return;

    if (m == 0) {   // dummy point at index M: zero weights, zero y
        float4 z = make_float4(0.f, 0.f, 0.f, 0.f);
        #pragma unroll
        for (int q = 0; q < 4; q++) { pnt[(size_t)M * 4 + q] = z; yF4[(size_t)M * 4 + q] = z; }
    }

    float u = uv[2 * m], v = uv[2 * m + 1];
    const float c2g = (float)KGRID / 6.283185307179586f;
    float kx = u * c2g, ky = v * c2g;
    float kmx = floorf(kx - 3.0f), kmy = floorf(ky - 3.0f);
    int x0m = (((int)kmx + 1) + 1024) & 1023;
    int y0m = (((int)kmy + 1) + 1024) & 1023;

    // ---- issue all bin atomics first (independent -> overlapped round-trips) ----
    int txA = x0m >> 3, txB = (txA + 1) & 127;
    int tyA = y0m >> 3, tyB = (tyA + 1) & 127;
    bool bx = (x0m & 7) >= 3;
    bool by = (y0m & 7) >= 3;
    int b0 = (txA << 7) | tyA;
    int b1 = (txA << 7) | tyB;
    int b2 = (txB << 7) | tyA;
    int b3 = (txB << 7) | tyB;
    int s0 = atomicAdd(&cnt[b0], 1);
    int s1 = by ? atomicAdd(&cnt[b1], 1) : -1;
    int s2 = bx ? atomicAdd(&cnt[b2], 1) : -1;
    int s3 = (bx && by) ? atomicAdd(&cnt[b3], 1) : -1;

    // ---- overlap the weight math with the atomic latency ----
    float inv = 1.0f / i0f_dev(BETAF);
    float s2c = inv * inv;
    float sc = wts[m] * s2c;

    float wx[JW], wy[JW];
    #pragma unroll
    for (int j = 0; j < JW; j++) {
        float dx = kx - kmx - 1.0f - (float)j;
        float rx = dx * (1.0f / 3.0f);
        float ax = fmaxf(1.0f - rx * rx, 0.0f);
        wx[j] = i0f_dev(BETAF * sqrtf(ax)) * sc;
        float dy = ky - kmy - 1.0f - (float)j;
        float ry = dy * (1.0f / 3.0f);
        float ay = fmaxf(1.0f - ry * ry, 0.0f);
        wy[j] = i0f_dev(BETAF * sqrtf(ay));
    }

    float4* p = pnt + (size_t)m * 4;
    p[0] = make_float4(wx[0], wx[1], wx[2], wx[3]);
    p[1] = make_float4(wx[4], wx[5], __int_as_float(x0m), __int_as_float(y0m));
    p[2] = make_float4(wy[0], wy[1], wy[2], wy[3]);
    p[3] = make_float4(wy[4], wy[5], 0.0f, 0.0f);

    #pragma unroll
    for (int bp = 0; bp < 4; bp++) {
        int bb = 2 * bp;
        yF4[(size_t)m * 4 + bp] = make_float4(
            yr[(size_t)bb * M + m],       yi[(size_t)bb * M + m],
            yr[(size_t)(bb + 1) * M + m], yi[(size_t)(bb + 1) * M + m]);
    }

    // ---- list stores (each waits only on its own slot) ----
    if ((unsigned)s0 < CAP) list[b0 * CAP + s0] = m;
    if ((unsigned)s1 < CAP) list[b1 * CAP + s1] = m;
    if ((unsigned)s2 < CAP) list[b2 * CAP + s2] = m;
    if ((unsigned)s3 < CAP) list[b3 * CAP + s3] = m;
}

// ---------- Phase B: gather-gridding, lane=cell, register accumulation ----------
// One wave per 8x8 tile; acc fp32, flush fp16 planes. Depth-3 prefetch (y loads
// are wave-uniform -> s_load; 3 stages cover ~200cyc L2 latency).
__global__ __launch_bounds__(256) void grid_tile(
    const float* __restrict__ pnt1, const float4* __restrict__ yF4,
    const int* __restrict__ cnt, const int* __restrict__ list,
    __half2* __restrict__ gH, int M)
{
    int lane = threadIdx.x & 63;
    int wid  = threadIdx.x >> 6;
    int tile = blockIdx.x * 4 + wid;
    int tx0 = (tile >> 7) << 3;
    int ty0 = (tile & 127) << 3;
    int lx = lane >> 3, ly = lane & 7;
    int slot = lane & 15;

    float2 acc[NB];
    #pragma unroll
    for (int b = 0; b < NB; b++) acc[b] = make_float2(0.f, 0.f);

    int n = cnt[tile]; if (n > CAP) n = CAP;
    const int* lst = list + tile * CAP;

    // preload index list into 2 VGPRs (slots beyond n -> dummy M)
    int lv0 = (lane < n) ? lst[lane] : M;
    int lv1 = (64 + lane < n && 64 + lane < CAP) ? lst[64 + lane] : M;

    #define FETCH_M(i) __builtin_amdgcn_readlane(((i) < 64) ? lv0 : lv1, (i) & 63)

    int   mA = FETCH_M(0), mB = FETCH_M(1), mC = FETCH_M(2);
    float pwA = pnt1[(size_t)mA * 16 + slot];
    float pwB = pnt1[(size_t)mB * 16 + slot];
    float pwC = pnt1[(size_t)mC * 16 + slot];
    float4 yA0 = yF4[(size_t)mA * 4 + 0], yA1 = yF4[(size_t)mA * 4 + 1],
           yA2 = yF4[(size_t)mA * 4 + 2], yA3 = yF4[(size_t)mA * 4 + 3];
    float4 yB0 = yF4[(size_t)mB * 4 + 0], yB1 = yF4[(size_t)mB * 4 + 1],
           yB2 = yF4[(size_t)mB * 4 + 2], yB3 = yF4[(size_t)mB * 4 + 3];
    float4 yC0 = yF4[(size_t)mC * 4 + 0], yC1 = yF4[(size_t)mC * 4 + 1],
           yC2 = yF4[(size_t)mC * 4 + 2], yC3 = yF4[(size_t)mC * 4 + 3];

    for (int i = 0; i < n; i++) {
        int mD = FETCH_M(i + 3);
        float pwD = pnt1[(size_t)mD * 16 + slot];
        float4 yD0 = yF4[(size_t)mD * 4 + 0], yD1 = yF4[(size_t)mD * 4 + 1],
               yD2 = yF4[(size_t)mD * 4 + 2], yD3 = yF4[(size_t)mD * 4 + 3];

        int pwb = __float_as_int(pwA);
        int x0 = __builtin_amdgcn_readlane(pwb, 6);
        int y0 = __builtin_amdgcn_readlane(pwb, 7);
        int j1 = (tx0 + lx - x0) & 1023;
        int j2 = (ty0 + ly - y0) & 1023;
        int i1 = (j1 < 6) ? j1 : 15;            // slot 15 = 0
        int i2 = (j2 < 6) ? (j2 + 8) : 14;      // slot 14 = 0
        float wx = __int_as_float(__builtin_amdgcn_ds_bpermute(i1 << 2, pwb));
        float wy = __int_as_float(__builtin_amdgcn_ds_bpermute(i2 << 2, pwb));
        float w = wx * wy;

        acc[0].x = fmaf(w, yA0.x, acc[0].x); acc[0].y = fmaf(w, yA0.y, acc[0].y);
        acc[1].x = fmaf(w, yA0.z, acc[1].x); acc[1].y = fmaf(w, yA0.w, acc[1].y);
        acc[2].x = fmaf(w, yA1.x, acc[2].x); acc[2].y = fmaf(w, yA1.y, acc[2].y);
        acc[3].x = fmaf(w, yA1.z, acc[3].x); acc[3].y = fmaf(w, yA1.w, acc[3].y);
        acc[4].x = fmaf(w, yA2.x, acc[4].x); acc[4].y = fmaf(w, yA2.y, acc[4].y);
        acc[5].x = fmaf(w, yA2.z, acc[5].x); acc[5].y = fmaf(w, yA2.w, acc[5].y);
        acc[6].x = fmaf(w, yA3.x, acc[6].x); acc[6].y = fmaf(w, yA3.y, acc[6].y);
        acc[7].x = fmaf(w, yA3.z, acc[7].x); acc[7].y = fmaf(w, yA3.w, acc[7].y);

        pwA = pwB; yA0 = yB0; yA1 = yB1; yA2 = yB2; yA3 = yB3;
        pwB = pwC; yB0 = yC0; yB1 = yC1; yB2 = yC2; yB3 = yC3;
        pwC = pwD; yC0 = yD0; yC1 = yD1; yC2 = yD2; yC3 = yD3;
    }
    #undef FETCH_M

    // flush fp16: tiles partition the grid -> every cell written exactly once
    size_t cell = ((size_t)(tx0 + lx) << 10) + (size_t)(ty0 + ly);
    #pragma unroll
    for (int b = 0; b < NB; b++)
        gH[((size_t)b << 20) + cell] = __float22half2_rn(acc[b]);
}

// ---------- Stockham radix-2 1024-pt inverse (e^{+i}) FFT in LDS ----------
__device__ __forceinline__ void fft1024_inv(float2* X, float2* Y, const float2* W, int tid)
{
    float2* src = X;
    float2* dst = Y;
    #pragma unroll
    for (int stage = 0; stage < 10; stage++) {
        const int s = 1 << stage;
        __syncthreads();
        #pragma unroll
        for (int h = 0; h < 2; h++) {
            int t  = tid + (h << 8);
            int sp = t & ~(s - 1);
            float2 c0 = src[t];
            float2 c1 = src[t + 512];
            float2 sum = make_float2(c0.x + c1.x, c0.y + c1.y);
            float2 dif = make_float2(c0.x - c1.x, c0.y - c1.y);
            float2 w = W[sp];
            dst[t + sp]     = sum;
            dst[t + sp + s] = make_float2(w.x * dif.x - w.y * dif.y,
                                          w.x * dif.y + w.y * dif.x);
        }
        float2* tmp = src; src = dst; dst = tmp;
    }
    __syncthreads();
}

// ---------- Pass 1 (fused Hermitian pack, mirror-paired): rows k2 -> x2 ----------
// Block g handles 8 output rows: {4g..4g+3} and {1020-4g..1023-4g}; mirror rows
// reuse the base rows' sources (L2 hits) -> ~10 unique row reads per plane.
__global__ __launch_bounds__(256) void fft_pass1(const __half2* __restrict__ gH,
                                                 __half2* __restrict__ T)
{
    __shared__ float2 A[1024];
    __shared__ float2 Bb[1024];
    __shared__ float2 W[512];
    __shared__ __half2 R[8][512];

    int blk = blockIdx.x;
    int p   = blk >> 7;          // 4 packed plane-pairs
    int g   = blk & 127;
    int tid = threadIdx.x;

    #pragma unroll
    for (int h = 0; h < 2; h++) {
        int j = tid + (h << 8);
        float sn, cn;
        __sincosf(6.283185307179586f * (float)j * (1.0f / 1024.0f), &sn, &cn);
        W[j] = make_float2(cn, sn);
    }

    const __half2* gA = gH + ((size_t)(2 * p)     << 20);
    const __half2* gB = gH + ((size_t)(2 * p + 1) << 20);

    for (int f = 0; f < 8; f++) {
        int k1  = (f < 4) ? (4 * g + f) : (1020 - 4 * g + (f - 4));
        int nk1 = (1024 - k1) & 1023;
        const __half2* rA  = gA + ((size_t)k1  << 10);
        const __half2* rAn = gA + ((size_t)nk1 << 10);
        const __half2* rB  = gB + ((size_t)k1  << 10);
        const __half2* rBn = gB + ((size_t)nk1 << 10);
        __syncthreads();
        #pragma unroll
        for (int h = 0; h < 4; h++) {
            int k2  = tid + (h << 8);
            int nk2 = (1024 - k2) & 1023;
            float2 va  = __half22float2(rA[k2]);
            float2 van = __half22float2(rAn[nk2]);
            float2 vb  = __half22float2(rB[k2]);
            float2 vbn = __half22float2(rBn[nk2]);
            A[k2] = make_float2(0.5f * (va.x + van.x) - 0.5f * (vb.y - vbn.y),
                                0.5f * (va.y - van.y) + 0.5f * (vb.x + vbn.x));
        }
        fft1024_inv(A, Bb, W, tid);
        #pragma unroll
        for (int h = 0; h < 2; h++) {
            int xo2 = tid + (h << 8);
            R[f][xo2] = __float22half2_rn(A[(xo2 + 768) & 1023]);
        }
    }
    __syncthreads();

    // T layout: half2 T[p][xo2][k1]; both quads contiguous -> 16B stores
    #pragma unroll
    for (int h = 0; h < 2; h++) {
        int xo2 = tid + (h << 8);
        __half2* Trow = T + (((size_t)p * 512 + xo2) << 10);
        int4 q0, q1;
        q0.x = *(const int*)&R[0][xo2]; q0.y = *(const int*)&R[1][xo2];
        q0.z = *(const int*)&R[2][xo2]; q0.w = *(const int*)&R[3][xo2];
        q1.x = *(const int*)&R[4][xo2]; q1.y = *(const int*)&R[5][xo2];
        q1.z = *(const int*)&R[6][xo2]; q1.w = *(const int*)&R[7][xo2];
        *(int4*)(Trow + 4 * g)          = q0;
        *(int4*)(Trow + (1020 - 4 * g)) = q1;
    }
}

// ---------- de-apodization (matches _deapod) ----------
__device__ __forceinline__ float apodf(int n) {
    float x  = ((float)n - 256.0f) * (1.0f / 1024.0f);
    float px = 3.14159265358979f * 6.0f * x;
    float t  = BETAF * BETAF - px * px;
    float st = sqrtf(fabsf(t));
    float num = (t > 0.0f) ? sinhf(st) : __sinf(st);
    return num / fmaxf(st, 1e-6f);
}

// ---------- Pass 2: columns (k1 -> x1) of packed planes, 4 cols/block;
// real -> batch 2p, imag -> batch 2p+1; coalesced float4 stores ----------
__global__ __launch_bounds__(256) void fft_pass2(const __half2* __restrict__ T,
                                                 float* __restrict__ out)
{
    __shared__ float2 A[1024];
    __shared__ float2 Bb[1024];
    __shared__ float2 W[512];
    __shared__ float2 R[4][512];

    int blk = blockIdx.x;
    int p   = blk >> 7;
    int xg  = blk & 127;
    int tid = threadIdx.x;

    #pragma unroll
    for (int h = 0; h < 2; h++) {
        int j = tid + (h << 8);
        float sn, cn;
        __sincosf(6.283185307179586f * (float)j * (1.0f / 1024.0f), &sn, &cn);
        W[j] = make_float2(cn, sn);
    }

    float a2[4];
    #pragma unroll
    for (int r = 0; r < 4; r++) a2[r] = apodf((xg << 2) + r);

    for (int r = 0; r < 4; r++) {
        int xo2 = (xg << 2) + r;
        const __half2* row = T + (((size_t)p * 512 + xo2) << 10);
        __syncthreads();
        #pragma unroll
        for (int h = 0; h < 4; h++) {
            int i = tid + (h << 8);
            A[i] = __half22float2(row[i]);
        }
        fft1024_inv(A, Bb, W, tid);
        #pragma unroll
        for (int h = 0; h < 2; h++) {
            int xo1 = tid + (h << 8);
            float2 v = A[(xo1 + 768) & 1023];
            R[r][xo1] = make_float2(v.x / a2[r], v.y / a2[r]);
        }
    }
    __syncthreads();

    int b0 = 2 * p;
    #pragma unroll
    for (int h = 0; h < 2; h++) {
        int xo1 = tid + (h << 8);
        float inva1 = 1.0f / apodf(xo1);
        float2 f0 = R[0][xo1], f1 = R[1][xo1], f2 = R[2][xo1], f3 = R[3][xo1];
        float4* o0 = (float4*)(out + (((size_t)b0 * 512 + xo1) << 9) + (xg << 2));
        float4* o1 = (float4*)(out + (((size_t)(b0 + 1) * 512 + xo1) << 9) + (xg << 2));
        *o0 = make_float4(f0.x * inva1, f1.x * inva1, f2.x * inva1, f3.x * inva1);
        *o1 = make_float4(f0.y * inva1, f1.y * inva1, f2.y * inva1, f3.y * inva1);
    }
}

// ---------- host launch ----------
extern "C" void kernel_launch(void* const* d_in, const int* in_sizes, int n_in,
                              void* d_out, int out_size, void* d_ws, size_t ws_size,
                              hipStream_t stream)
{
    const float* yr  = (const float*)d_in[0];
    const float* yi  = (const float*)d_in[1];
    const float* uv  = (const float*)d_in[2];
    const float* wts = (const float*)d_in[3];

    int M = in_sizes[3];

    // ws layout (non-overlapping):
    //  [0,32)MB : gH (8 fp16 planar grids, 4 MB each)
    //  [32,40)MB: T (fp16, 8 MB)
    //  [64,96)MB: prep/grid scratch (cnt/list/yF4/pnt)
    __half2* gH = (__half2*)d_ws;
    __half2* T  = (__half2*)((char*)d_ws + ((size_t)32 << 20));
    char*    p2 = (char*)d_ws + ((size_t)64 << 20);
    int*    cnt  = (int*)p2;                                     // 64 KB
    int*    list = (int*)(p2 + 65536);                           // 6.29 MB
    float4* yF4  = (float4*)(p2 + 6553600);                      // 12.8 MB (M+1 pts)
    float4* pnt  = (float4*)(p2 + 19500032);                     // 12.8 MB (M+1 pts)

    hipMemsetAsync(cnt, 0, NBIN * sizeof(int), stream);
    prep_kernel<<<dim3((M + 255) / 256), dim3(256), 0, stream>>>(
        yr, yi, uv, wts, yF4, pnt, cnt, list, M);
    grid_tile<<<dim3(NBIN / 4), dim3(256), 0, stream>>>(
        (const float*)pnt, (const float4*)yF4, cnt, list, gH, M);
    fft_pass1<<<dim3(4 * 128), dim3(256), 0, stream>>>(gH, T);
    fft_pass2<<<dim3(4 * 128), dim3(256), 0, stream>>>(T, (float*)d_out);
}